// Round 7
// baseline (946.251 us; speedup 1.0000x reference)
//
#include <hip/hip_runtime.h>

#define NB 2048
#define NT 1024

typedef _Float16 half2_t __attribute__((ext_vector_type(2)));
union F4H { float4 f; half2_t h[4]; };

// sigmoid / tanh via native exp2 + rcp
__device__ __forceinline__ float sig_fast(float x) {
    return __builtin_amdgcn_rcpf(1.0f + __builtin_amdgcn_exp2f(-1.4426950408889634f * x));
}
__device__ __forceinline__ float tanh_fast(float x) {
    return fmaf(2.0f, __builtin_amdgcn_rcpf(1.0f + __builtin_amdgcn_exp2f(-2.8853900817779268f * x)), -1.0f);
}

__global__ void zero_loss_kernel(float* out) { out[0] = 0.0f; }

#define LD4(P, i) (*(const float4*)&(P)[i])
#define FDOT(acc, w, hh) acc = __builtin_amdgcn_fdot2((w), (hh), (acc), false)
// volatile: cannot be duplicated, sunk, or deleted -> the weight loads are
// materialized exactly once, before the T-loop.
#define PINH(v) asm volatile("" : "+v"(v))

// one f32 float4 -> two packed half2
#define CVTQ(n0, n1, p, i) { float4 r_ = LD4(p, i); \
  n0.x=(_Float16)r_.x; n0.y=(_Float16)r_.y; n1.x=(_Float16)r_.z; n1.y=(_Float16)r_.w; }

// one 32-wide weight row as 16 named half2 (16 VGPRs), volatile-pinned
#define DECL_ROWH(n, src, row) \
  half2_t n##0,n##1,n##2,n##3,n##4,n##5,n##6,n##7,n##8,n##9,n##10,n##11,n##12,n##13,n##14,n##15; \
  CVTQ(n##0, n##1, src,(row)*32+ 0) CVTQ(n##2, n##3, src,(row)*32+ 4) \
  CVTQ(n##4, n##5, src,(row)*32+ 8) CVTQ(n##6, n##7, src,(row)*32+12) \
  CVTQ(n##8, n##9, src,(row)*32+16) CVTQ(n##10,n##11,src,(row)*32+20) \
  CVTQ(n##12,n##13,src,(row)*32+24) CVTQ(n##14,n##15,src,(row)*32+28) \
  PINH(n##0); PINH(n##1); PINH(n##2); PINH(n##3); PINH(n##4); PINH(n##5); PINH(n##6); PINH(n##7); \
  PINH(n##8); PINH(n##9); PINH(n##10); PINH(n##11); PINH(n##12); PINH(n##13); PINH(n##14); PINH(n##15);

// 8 dot2 (16 MACs) into two accumulators from one 16B LDS broadcast read
#define DOT4(aa, ab, wA0,wA1,wA2,wA3, wB0,wB1,wB2,wB3, U) \
  FDOT(aa, wA0, (U).h[0]); FDOT(ab, wB0, (U).h[0]); \
  FDOT(aa, wA1, (U).h[1]); FDOT(ab, wB1, (U).h[1]); \
  FDOT(aa, wA2, (U).h[2]); FDOT(ab, wB2, (U).h[2]); \
  FDOT(aa, wA3, (U).h[3]); FDOT(ab, wB3, (U).h[3]);

// min waves/EU = 1 -> 256-VGPR budget: the ~150-reg demand fits with zero
// spill/remat. Expect 1 wave/SIMD; 2048 waves drain in 2 occupancy rounds.
__global__ __launch_bounds__(64) __attribute__((amdgpu_waves_per_eu(1, 2)))
void decoder_lstm_kernel(const float* __restrict__ seq,    // (B,T,1)
                         const float* __restrict__ z,      // (B,32)
                         const float* __restrict__ w_ih0,  // (128,1)
                         const float* __restrict__ w_hh0,  // (128,32)
                         const float* __restrict__ b_ih0,  // (128,)
                         const float* __restrict__ b_hh0,  // (128,)
                         const float* __restrict__ w_ih1,  // (128,32)
                         const float* __restrict__ w_hh1,  // (128,32)
                         const float* __restrict__ b_ih1,  // (128,)
                         const float* __restrict__ b_hh1,  // (128,)
                         const float* __restrict__ w_out,  // (1,32)
                         const float* __restrict__ b_out,  // (1,)
                         float* __restrict__ out)          // [0]=loss, [1..]=recovered (B,T,1)
{
    const int b  = blockIdx.x;     // one wave per batch element
    const int l  = threadIdx.x;    // 0..63
    const int lo = l & 31;

    // 64 halves per row: slots 32..63 are padding so all lanes store unconditionally
    __shared__ float4 sh0f[8];
    __shared__ float4 sh1f[8];
    _Float16* sh0h = (_Float16*)sh0f;
    _Float16* sh1h = (_Float16*)sh1f;

    // lane<32 : rA=i-row, rB=g-row ; lane>=32: rA=f-row, rB=o-row
    const int rA = l;
    const int rB = l + 64;

    const float wih0A  = w_ih0[rA];
    const float wih0B  = w_ih0[rB];
    const float bias0A = b_ih0[rA] + b_hh0[rA];
    const float bias0B = b_ih0[rB] + b_hh0[rB];
    const float bias1A = b_ih1[rA] + b_hh1[rA];
    const float bias1B = b_ih1[rB] + b_hh1[rB];

    // branchless lane personality: gate B is tanh (lower) vs sigmoid (upper)
    const float m    = (l < 32) ? 1.0f : 0.0f;
    const float wOut = (l < 32) ? w_out[lo] : 0.0f;  // 0 upper -> clean reduction
    const float bOut = b_out[0];

    // 96 pinned half2 = 96 VGPRs of weights
    DECL_ROWH(w0A, w_hh0, rA)
    DECL_ROWH(w0B, w_hh0, rB)
    DECL_ROWH(wiA, w_ih1, rA)
    DECL_ROWH(wiB, w_ih1, rB)
    DECL_ROWH(whA, w_hh1, rA)
    DECL_ROWH(whB, w_hh1, rB)

    // init: h0 = c0 = h1 = c1 = z, pred = 0
    float zv = z[(size_t)b * 32 + lo];
    float cc0 = zv, cc1 = zv;
    sh0h[l] = (_Float16)zv;          // upper lanes land in padding
    sh1h[l] = (_Float16)zv;
    float pred = 0.0f, sse = 0.0f, xreg = 0.0f;

    const float* seq_b = seq + (size_t)b * NT;
    float* out_b = out + 1 + (size_t)b * NT;

    __builtin_amdgcn_wave_barrier();   // single wave: DS ops in-order; compiler fence only

    for (int t = 0; t < NT; ++t) {
        if ((t & 63) == 0) xreg = seq_b[t + l];   // coalesced 256B load per 64 steps

        // prefetch both broadcast operands written by the previous step
        F4H U0, U1, U2, U3, X0, X1, X2, X3;
        U0.f = sh0f[0]; U1.f = sh0f[1]; U2.f = sh0f[2]; U3.f = sh0f[3];   // h0
        X0.f = sh1f[0]; X1.f = sh1f[1]; X2.f = sh1f[2]; X3.f = sh1f[3];   // h1

        // -------- cell 0: gates = pred*w_ih0 + h0 @ w_hh0^T + b0
        float a0 = fmaf(pred, wih0A, bias0A), a1 = 0.0f;
        float b0 = fmaf(pred, wih0B, bias0B), b1 = 0.0f;
        DOT4(a0, b0, w0A0,w0A1,w0A2,w0A3,     w0B0,w0B1,w0B2,w0B3,     U0);
        DOT4(a1, b1, w0A4,w0A5,w0A6,w0A7,     w0B4,w0B5,w0B6,w0B7,     U1);
        DOT4(a0, b0, w0A8,w0A9,w0A10,w0A11,   w0B8,w0B9,w0B10,w0B11,   U2);
        DOT4(a1, b1, w0A12,w0A13,w0A14,w0A15, w0B12,w0B13,w0B14,w0B15, U3);
        float gA = a0 + a1;   // lane<32: i ; lane>=32: f
        float gB = b0 + b1;   // lane<32: g ; lane>=32: o

        float sA  = sig_fast(gA);
        float gBx = fmaf(m, gB, gB);                  // 2*gB lower, gB upper
        float sB  = sig_fast(gBx);
        float vB  = fmaf(m, sB - 1.0f, sB);           // tanh(g) lower / sig(o) upper

        float fOrI = __shfl_xor(sA, 32);   // lane<32 receives sig(f)
        float oOrG = __shfl_xor(vB, 32);   // lane<32 receives sig(o)
        cc0 = fmaf(fOrI, cc0, sA * vB);          // lanes<32 valid
        float h0n = oOrG * tanh_fast(cc0);
        sh0h[l] = (_Float16)h0n;                 // upper garbage -> padding (finite)
        __builtin_amdgcn_wave_barrier();

        // -------- cell 1: gates = h0n @ w_ih1^T + h1 @ w_hh1^T + b1
        F4H V0, V1, V2, V3;
        V0.f = sh0f[0]; V1.f = sh0f[1]; V2.f = sh0f[2]; V3.f = sh0f[3];   // h0n
        float cA0 = bias1A, cA1 = 0.0f;
        float cB0 = bias1B, cB1 = 0.0f;
        DOT4(cA0, cB0, wiA0,wiA1,wiA2,wiA3,     wiB0,wiB1,wiB2,wiB3,     V0);
        DOT4(cA1, cB1, wiA4,wiA5,wiA6,wiA7,     wiB4,wiB5,wiB6,wiB7,     V1);
        DOT4(cA0, cB0, wiA8,wiA9,wiA10,wiA11,   wiB8,wiB9,wiB10,wiB11,   V2);
        DOT4(cA1, cB1, wiA12,wiA13,wiA14,wiA15, wiB12,wiB13,wiB14,wiB15, V3);
        DOT4(cA0, cB0, whA0,whA1,whA2,whA3,     whB0,whB1,whB2,whB3,     X0);
        DOT4(cA1, cB1, whA4,whA5,whA6,whA7,     whB4,whB5,whB6,whB7,     X1);
        DOT4(cA0, cB0, whA8,whA9,whA10,whA11,   whB8,whB9,whB10,whB11,   X2);
        DOT4(cA1, cB1, whA12,whA13,whA14,whA15, whB12,whB13,whB14,whB15, X3);
        float g1A = cA0 + cA1;
        float g1B = cB0 + cB1;

        float s1A  = sig_fast(g1A);
        float g1Bx = fmaf(m, g1B, g1B);
        float s1B  = sig_fast(g1Bx);
        float v1B  = fmaf(m, s1B - 1.0f, s1B);

        float f1 = __shfl_xor(s1A, 32);
        float o1 = __shfl_xor(v1B, 32);
        cc1 = fmaf(f1, cc1, s1A * v1B);
        float h1n = o1 * tanh_fast(cc1);          // lanes<32 valid
        sh1h[l] = (_Float16)h1n;

        // pred = b_out + sum_j w_out[j]*h1n[j] (upper lanes contribute 0)
        float term = wOut * h1n;
        term += __shfl_xor(term, 1);
        term += __shfl_xor(term, 2);
        term += __shfl_xor(term, 4);
        term += __shfl_xor(term, 8);
        term += __shfl_xor(term, 16);
        term += __shfl_xor(term, 32);
        pred = term + bOut;
        __builtin_amdgcn_wave_barrier();

        out_b[t] = pred;                          // uniform value+addr: 1 transaction
        float d    = xreg - pred;
        float dsel = ((t & 63) == l) ? d : 0.0f;  // lane t&63 owns step t's residual
        sse = fmaf(dsel, d, sse);
    }

    // wave-wide SSE reduction, one atomic per block
    sse += __shfl_xor(sse, 1);
    sse += __shfl_xor(sse, 2);
    sse += __shfl_xor(sse, 4);
    sse += __shfl_xor(sse, 8);
    sse += __shfl_xor(sse, 16);
    sse += __shfl_xor(sse, 32);
    if (l == 0) {
        atomicAdd(out, sse * (1.0f / ((float)NB * (float)NT)));  // 1/(B*T) = 2^-21 exact
    }
}

extern "C" void kernel_launch(void* const* d_in, const int* in_sizes, int n_in,
                              void* d_out, int out_size, void* d_ws, size_t ws_size,
                              hipStream_t stream) {
    const float* seq   = (const float*)d_in[0];
    const float* z     = (const float*)d_in[1];
    // d_in[2] = lengths (unused; reference ignores it)
    const float* w_ih0 = (const float*)d_in[3];
    const float* w_hh0 = (const float*)d_in[4];
    const float* b_ih0 = (const float*)d_in[5];
    const float* b_hh0 = (const float*)d_in[6];
    const float* w_ih1 = (const float*)d_in[7];
    const float* w_hh1 = (const float*)d_in[8];
    const float* b_ih1 = (const float*)d_in[9];
    const float* b_hh1 = (const float*)d_in[10];
    const float* w_out = (const float*)d_in[11];
    const float* b_out = (const float*)d_in[12];
    float* out = (float*)d_out;

    hipLaunchKernelGGL(zero_loss_kernel, dim3(1), dim3(1), 0, stream, out);
    hipLaunchKernelGGL(decoder_lstm_kernel, dim3(NB), dim3(64), 0, stream,
                       seq, z, w_ih0, w_hh0, b_ih0, b_hh0,
                       w_ih1, w_hh1, b_ih1, b_hh1, w_out, b_out, out);
}